// Round 17
// baseline (47.290 us; speedup 1.0000x reference)
//
#include <hip/hip_runtime.h>
#include <stdint.h>

// ---------------------------------------------------------------------------
// FractalLinear: IFS chaos game (JAX threefry-exact) + bilinear gather/scatter
// Round 17 = R16 (best, 40.5us) + L2 PRE-TOUCH of the next row:
//   4x global_load_lds(16B) per thread stream row r+1 into L2 via a 1KB
//   dummy LDS sink (no VGPRs, no waits; vmcnt never drained in-loop).
//   The scattered gathers then hit L2 / MSHR-merge -> HBM request stream
//   becomes ~sequential. Trades 51MB random fetch (1.4TB/s = the measured
//   wall) for ~130MB sequential (6.3TB/s). NT stores bypass L2 (keeps the
//   4MB/XCD window for touch lines: 64 blocks x 64KB = 4MB exactly).
// R16 carried: dbuf acc[2][8K], 1 barrier/row, bias in regs, floatx2 taps,
// LDS-only barriers, loads-before-stores issue order.
// ---------------------------------------------------------------------------
#ifndef PRNG_PARTITIONABLE
#define PRNG_PARTITIONABLE 1
#endif

namespace {

constexpr int kH  = 8192;
constexpr int kW  = 16384;
constexpr int kNT = 8;
constexpr int kNP = 1000;
constexpr int kCI = 10;
constexpr int kTh  = 1024;       // threads per apply block
constexpr int kRPB = 4;          // rows per apply block -> 512 blocks resident

typedef float floatx4 __attribute__((ext_vector_type(4)));  // nontemporal-OK
typedef float floatx2 __attribute__((ext_vector_type(2), aligned(4)));

// Raw barrier: wait only on LDS ops; global loads/stores stay in flight.
#define BAR_LDS() asm volatile("s_waitcnt lgkmcnt(0)\n\ts_barrier" ::: "memory")

__device__ __forceinline__ uint32_t rotl32(uint32_t x, int n) {
  return (x << n) | (x >> (32 - n));
}

// Threefry-2x32, 20 rounds (Random123 / JAX convention).
__device__ void threefry2x32(uint32_t k0, uint32_t k1, uint32_t c0, uint32_t c1,
                             uint32_t& o0, uint32_t& o1) {
  const uint32_t ks2 = k0 ^ k1 ^ 0x1BD11BDAu;
  uint32_t x0 = c0 + k0, x1 = c1 + k1;
#define TF_R(r) { x0 += x1; x1 = rotl32(x1, (r)); x1 ^= x0; }
  TF_R(13) TF_R(15) TF_R(26) TF_R(6)
  x0 += k1;  x1 += ks2 + 1u;
  TF_R(17) TF_R(29) TF_R(16) TF_R(24)
  x0 += ks2; x1 += k0 + 2u;
  TF_R(13) TF_R(15) TF_R(26) TF_R(6)
  x0 += k0;  x1 += k1 + 3u;
  TF_R(17) TF_R(29) TF_R(16) TF_R(24)
  x0 += k1;  x1 += ks2 + 4u;
  TF_R(13) TF_R(15) TF_R(26) TF_R(6)
  x0 += ks2; x1 += k0 + 5u;
#undef TF_R
  o0 = x0; o1 = x1;
}

__device__ __forceinline__ uint32_t random_bits32(uint32_t k0, uint32_t k1,
                                                  uint32_t i, uint32_t size) {
#if PRNG_PARTITIONABLE
  uint32_t o0, o1;
  threefry2x32(k0, k1, 0u /* hi(i) */, i, o0, o1);
  (void)size;
  return o0 ^ o1;
#else
  const uint32_t half = size / 2u;
  const uint32_t j = (i < half) ? i : (i - half);
  uint32_t o0, o1;
  threefry2x32(k0, k1, j, j + half, o0, o1);
  return (i < half) ? o0 : o1;
#endif
}

__device__ __forceinline__ float u01(uint32_t bits) {
  return __uint_as_float((bits >> 9) | 0x3f800000u) - 1.0f;
}

// x86 cvttss2si semantics: out-of-range / NaN -> INT_MIN (matches CPU-ref).
__device__ __forceinline__ int cvt_f32_i32_x86(float v) {
  if (!(v >= -2147483648.0f && v < 2147483648.0f)) return (int)0x80000000;
  return (int)v;
}

// ---------------------------------------------------------------------------
// Kernel 1: chaos game, 8 lanes per point (one transform each).
// ---------------------------------------------------------------------------
__global__ __launch_bounds__(256) void fractal_chaos(
    const float* __restrict__ dna, int4* __restrict__ rec) {
  const int gid  = blockIdx.x * blockDim.x + threadIdx.x;
  const int n    = gid >> 3;
  const int lane = gid & 7;
  if (n >= kNP) return;

  uint32_t kp0, kp1, kg0, kg1;
#if PRNG_PARTITIONABLE
  threefry2x32(0u, 1u, 0u, 0u, kp0, kp1);
  threefry2x32(0u, 1u, 0u, 1u, kg0, kg1);
#else
  uint32_t a0, a1, b0, b1;
  threefry2x32(0u, 1u, 0u, 2u, a0, a1);
  threefry2x32(0u, 1u, 1u, 3u, b0, b1);
  kp0 = a0; kp1 = b0; kg0 = a1; kg1 = b1;
#endif

  const float A  = dna[lane * 7 + 0], Bb = dna[lane * 7 + 1];
  const float C  = dna[lane * 7 + 2], D  = dna[lane * 7 + 3];
  const float E  = dna[lane * 7 + 4], F  = dna[lane * 7 + 5];
  const float P  = dna[lane * 7 + 6];

  float z[kCI];
  #pragma unroll
  for (int i = 0; i < kCI; ++i) {
    uint32_t ki0, ki1;
    threefry2x32(kg0, kg1, 0u, (uint32_t)i, ki0, ki1);   // fold_in(kg, i)
    const uint32_t bb = random_bits32(ki0, ki1, (uint32_t)(n * kNT + lane),
                                      (uint32_t)(kNP * kNT));
    const float u = fmaxf(u01(bb), 1.17549435e-38f);
    const float g = -logf(-logf(u));
    z[i] = P + g;
  }

  const uint32_t bx = random_bits32(kp0, kp1, (uint32_t)(2 * n),     2u * kNP);
  const uint32_t by = random_bits32(kp0, kp1, (uint32_t)(2 * n + 1), 2u * kNP);
  float px = u01(bx) * 2.0f - 1.0f;
  float py = u01(by) * 2.0f - 1.0f;

  #pragma unroll
  for (int i = 0; i < kCI; ++i) {
    // argmax over the 8 lanes, first-index tiebreak (matches jnp.argmax)
    float zb = z[i];
    int   bt = lane;
    #pragma unroll
    for (int m = 1; m < 8; m <<= 1) {
      const float zo = __shfl_xor(zb, m, 8);
      const int   to = __shfl_xor(bt, m, 8);
      if (zo > zb || (zo == zb && to < bt)) { zb = zo; bt = to; }
    }
    const float A_ = __shfl(A,  bt, 8), B_ = __shfl(Bb, bt, 8);
    const float C_ = __shfl(C,  bt, 8), D_ = __shfl(D,  bt, 8);
    const float E_ = __shfl(E,  bt, 8), F_ = __shfl(F,  bt, 8);
    const float nx = A_ * px + B_ * py + E_;
    const float ny = C_ * px + D_ * py + F_;
    px = nx; py = ny;
  }

  if (lane == 0) {
    const float xc = ((px + 1.0f) * 0.5f) * (float)(kW - 1);
    const float yc = ((py + 1.0f) * 0.5f) * (float)(kH - 1);
    int xl = cvt_f32_i32_x86(floorf(xc));
    int yl = cvt_f32_i32_x86(floorf(yc));
    xl = min(max(xl, 0), kW - 2);
    yl = min(max(yl, 0), kH - 2);
    const float xw = xc - (float)xl;   // NOT clipped (matches reference)
    const float yw = yc - (float)yl;
    rec[n] = make_int4(xl, __float_as_int(xw), yl, __float_as_int(yw));
  }
}

// ---------------------------------------------------------------------------
// Kernel 2: R16 double-buffered pipelined apply + L2 pre-touch of next row.
// ---------------------------------------------------------------------------
__global__ __launch_bounds__(kTh) void fractal_apply(
    const float* __restrict__ x, const float* __restrict__ bias,
    const int4* __restrict__ rec, float* __restrict__ out, int B) {
  __shared__ __align__(16) float acc[2][kH];     // 64 KB -> 2 blocks/CU
  __shared__ __align__(16) float dummy[256];     // 1 KB touch sink (never read)
  const int tid = threadIdx.x;
  const int r0  = blockIdx.x * kRPB;

  // per-thread point record (threads 0..999)
  const bool hav = tid < kNP;
  int xl = 0, yl = 0;
  float xw = 0.f, yw = 0.f;
  if (hav) {
    const int4 rr = rec[tid];
    xl = rr.x; xw = __int_as_float(rr.y);
    yl = rr.z; yw = __int_as_float(rr.w);
  }
  const float xw0 = 1.0f - xw;
  const float w0  = 1.0f - yw;

  // L2 pre-touch of row r0: 4 x 16B per thread = 64 KB, sequential.
  // global_load_lds -> dummy sink: no VGPR result, nothing ever waits on it.
  if (r0 < B) {
    const float* xn = x + (size_t)r0 * kW;
    #pragma unroll
    for (int j = 0; j < 4; ++j)
      __builtin_amdgcn_global_load_lds(
          (const __attribute__((address_space(1))) void*)(xn +
              ((size_t)(tid + j * kTh) << 2)),
          (__attribute__((address_space(3))) void*)dummy, 16, 0, 0);
  }

  // prologue gather for row r0 (merges with the in-flight touch lines)
  floatx2 t = (floatx2)0.f;
  if (hav && r0 < B) t = *(const floatx2*)(x + (size_t)r0 * kW + xl);

  // preload bias into registers: epilogue issues NO global loads
  const floatx4* __restrict__ bias4 = reinterpret_cast<const floatx4*>(bias);
  floatx4 breg[2];
  breg[0] = bias4[tid];
  breg[1] = bias4[tid + kTh];

  // zero both accumulators (LDS only; overlaps the VMEM in flight)
  float4* acc4 = reinterpret_cast<float4*>(&acc[0][0]);
  #pragma unroll
  for (int j = 0; j < 4; ++j)
    acc4[tid + j * kTh] = make_float4(0.f, 0.f, 0.f, 0.f);

  BAR_LDS();   // zeros visible; all VMEM stays in flight

  #pragma unroll
  for (int it = 0; it < kRPB; ++it) {
    const int r = r0 + it;
    if (r >= B) break;                        // block-uniform, barrier-safe
    const int p = it & 1;

    // scatter current row into acc[p] (vmcnt releases this row's 8B load)
    if (hav) {
      const float xv = t.x * xw0 + t.y * xw;
      atomicAdd(&acc[p][yl],     xv * w0);
      atomicAdd(&acc[p][yl + 1], xv * yw);
    }

    // touch + gather row r+1 (loads before the epilogue's NT stores)
    if (it + 1 < kRPB && r + 1 < B) {
      const float* xn = x + (size_t)(r + 1) * kW;
      #pragma unroll
      for (int j = 0; j < 4; ++j)
        __builtin_amdgcn_global_load_lds(
            (const __attribute__((address_space(1))) void*)(xn +
                ((size_t)(tid + j * kTh) << 2)),
            (__attribute__((address_space(3))) void*)dummy, 16, 0, 0);
      if (hav) t = *(const floatx2*)(xn + xl);
    }

    BAR_LDS();   // scatters into acc[p] visible; VMEM stays in flight

    // epilogue: out = acc[p]/1000 + bias(reg), NT store, fused rezero.
    float4* accp = reinterpret_cast<float4*>(&acc[p][0]);
    floatx4* __restrict__ out4 =
        reinterpret_cast<floatx4*>(out + (size_t)r * kH);
    #pragma unroll
    for (int j = 0; j < 2; ++j) {
      const int g = tid + j * kTh;
      const float4 a = accp[g];
      floatx4 o;
      o.x = a.x / 1000.0f + breg[j].x;
      o.y = a.y / 1000.0f + breg[j].y;
      o.z = a.z / 1000.0f + breg[j].z;
      o.w = a.w / 1000.0f + breg[j].w;
      __builtin_nontemporal_store(o, &out4[g]);
      accp[g] = make_float4(0.f, 0.f, 0.f, 0.f);   // fused rezero
    }
    // no second barrier: next iteration uses acc[p^1]; rezero of acc[p]
    // is ordered before scatter(it+2) by BAR(it+1).
  }
}

}  // namespace

extern "C" void kernel_launch(void* const* d_in, const int* in_sizes, int n_in,
                              void* d_out, int out_size, void* d_ws, size_t ws_size,
                              hipStream_t stream) {
  const float* x    = (const float*)d_in[0];   // (2048, 16384)
  const float* dna  = (const float*)d_in[1];   // (56,)
  const float* bias = (const float*)d_in[2];   // (8192,)
  float* out = (float*)d_out;                  // (2048, 8192)
  int4* rec = (int4*)d_ws;                     // 1000 * 16B scratch

  fractal_chaos<<<(kNP * 8 + 255) / 256, 256, 0, stream>>>(dna, rec);

  const int B = in_sizes[0] / kW;              // 2048
  fractal_apply<<<(B + kRPB - 1) / kRPB, kTh, 0, stream>>>(x, bias, rec,
                                                           out, B);
}